// Round 8
// baseline (650.137 us; speedup 1.0000x reference)
//
#include <hip/hip_runtime.h>
#include <math.h>

#define D_DIM 2048
#define NE    64
#define NTOK  16384
#define TK    8
#define TOKB  64                 // tokens per block (all 8 waves share them)
#define BT    512                // 8 waves
#define CHD   128                // d per chunk (block-wide); wave ks owns 16 of them
#define NCHK  (D_DIM / CHD)      // 16 chunks
#define NQR   (CHD / 4)          // 32 quads per expert row per chunk
#define WCH   (NE * CHD)         // 8192 floats per w staging buffer (32 KB)

#define RROW  68                 // padded row (64 + 4) for reduction/topk tiles
#define SLICE (TOKB * RROW)      // 4352 floats
#define POOLF (4 * SLICE)        // 17408 floats = 69632 B  (>= 2*WCH = 16384)

#define OUT_I_OFF (NTOK * TK)
#define OUT_S_OFF (2 * NTOK * TK)

#define GLOBAL_AS __attribute__((address_space(1)))
#define LDS_AS    __attribute__((address_space(3)))

static __device__ __forceinline__ void async_copy16(const float* g, float* l) {
    // offset immediate ALWAYS 0 (r2 lesson).
    __builtin_amdgcn_global_load_lds((const GLOBAL_AS void*)g, (LDS_AS void*)l, 16, 0, 0);
}

// Block = 64 tokens x 64 experts x full K. 8 waves split each 128-d chunk
// (wave ks owns quads qL = ks*4..ks*4+3), sharing ONE 32 KB w-chunk in LDS.
// w: global_load_lds staged, XOR-swizzled on the GLOBAL side (slot qp of expert
// e holds logical quad qp ^ (e&7); read addr e*128 + ((qL^le)<<2) -> 8 distinct
// bank-quads covering all 32 banks, conflict-free broadcast). x: per-lane float4
// from L3 (8 distinct 16B lines/instr).
// r7 lesson: at 2 waves/SIMD (grid-pinned: 256 blocks = 1/CU) with VGPR=128 the
// compiler had zero spare regs -> no pipelining -> every qq-step ate raw L3
// latency (VALUBusy 32%). Fix: explicit ping-pong dbuf of BOTH operands
// (xiA/xiB via VMEM prefetched 1 step ahead + cross-chunk at qq=3; wjA/wjB via
// DS 1 step ahead). Live set ~224 regs < 256 spill line. CHD 64->128 halves
// barriers and doubles FMA run per exposure.
__global__ __launch_bounds__(BT, 1) void gate_fused(const float* __restrict__ x,
                                                    const float* __restrict__ w,
                                                    const float* __restrict__ gb,
                                                    float* __restrict__ out) {
    __shared__ __align__(16) float pool[POOLF];

    float* scores = out + OUT_S_OFF;
    const int tid  = threadIdx.x;
    const int lane = tid & 63;
    const int ks   = tid >> 6;     // wave id: which 16-d sub-slice of each chunk
    const int lt   = lane >> 3;    // token slot 0..7
    const int le   = lane & 7;     // expert slot 0..7
    const int tok0 = blockIdx.x * TOKB;

    // ---- staging map: thread covers quads m = tid + 512k, k<4, of the 2048-quad
    // chunk. m -> (e = m>>5 = e0+16k, qp = m&31); slot qp holds logical quad
    // qp ^ (e&7); (e0+16k)&7 == e0&7 so dq0 is k-invariant.
    const int e0  = tid >> 5;
    const int qp0 = tid & 31;
    const int dq0 = qp0 ^ (e0 & 7);
    const float* srcq[4];
#pragma unroll
    for (int k = 0; k < 4; ++k)
        srcq[k] = w + (size_t)(e0 + 16 * k) * D_DIM + (dq0 << 2);

    auto stage = [&](int c, int buf) {
        float* d = pool + buf * WCH + tid * 4;
#pragma unroll
        for (int k = 0; k < 4; ++k)
            async_copy16(srcq[k] + c * CHD, d + k * 2048);
    };

    // ---- x row pointers: tokens i*8+lt (8 same-lt lanes share each address)
    const float4* xq[8];
#pragma unroll
    for (int i = 0; i < 8; ++i)
        xq[i] = (const float4*)x + (size_t)(tok0 + i * 8 + lt) * (D_DIM / 4);

    float acc[8][8];
#pragma unroll
    for (int i = 0; i < 8; ++i)
#pragma unroll
        for (int j = 0; j < 8; ++j) acc[i][j] = 0.f;

    float4 xiA[8], xiB[8], wjA[8], wjB[8];
    const int qL0 = ks * 4;

    auto loadx = [&](float4 (&X)[8], int qidx) {
#pragma unroll
        for (int i = 0; i < 8; ++i) X[i] = xq[i][qidx];
    };
    auto loadw = [&](float4 (&W)[8], const float* wb, int qL) {
#pragma unroll
        for (int j = 0; j < 8; ++j)
            W[j] = *(const float4*)(wb + (j * 8 + le) * CHD + ((qL ^ le) << 2));
    };
    auto fmas = [&](float4 (&X)[8], float4 (&W)[8]) {
#pragma unroll
        for (int i = 0; i < 8; ++i) {
#pragma unroll
            for (int j = 0; j < 8; ++j) {
                acc[i][j] = fmaf(X[i].x, W[j].x, acc[i][j]);
                acc[i][j] = fmaf(X[i].y, W[j].y, acc[i][j]);
                acc[i][j] = fmaf(X[i].z, W[j].z, acc[i][j]);
                acc[i][j] = fmaf(X[i].w, W[j].w, acc[i][j]);
            }
        }
    };

    stage(0, 0);
    loadx(xiA, qL0);                         // chunk 0, qq 0 (x independent of staging)

    for (int c = 0; c < NCHK; ++c) {
        __syncthreads();                     // chunk-c w staged (issued 1 chunk ago)
        if (c + 1 < NCHK) stage(c + 1, (c + 1) & 1);
        const float* wb = pool + (c & 1) * WCH;
        const int qb = c * NQR + qL0;
        loadw(wjA, wb, qL0);
        // qq = 0
        loadx(xiB, qb + 1); loadw(wjB, wb, qL0 + 1);
        fmas(xiA, wjA);
        // qq = 1
        loadx(xiA, qb + 2); loadw(wjA, wb, qL0 + 2);
        fmas(xiB, wjB);
        // qq = 2
        loadx(xiB, qb + 3); loadw(wjB, wb, qL0 + 3);
        fmas(xiA, wjA);
        // qq = 3 (cross-chunk x prefetch: x doesn't depend on staging)
        if (c + 1 < NCHK) loadx(xiA, (c + 1) * NQR + qL0);
        fmas(xiB, wjB);
    }

    // ---- split-K reduction over the 8 waves (pool reused; padded rows) ----
    __syncthreads();
    if (ks >= 4) {                 // phase0: waves 4..7 store into slices 0..3
        float* pr = pool + (ks - 4) * SLICE;
#pragma unroll
        for (int i = 0; i < 8; ++i)
#pragma unroll
            for (int j = 0; j < 8; ++j)
                pr[(i * 8 + lt) * RROW + j * 8 + le] = acc[i][j];
    }
    __syncthreads();
    if (ks < 4) {                  // phase1: waves 0..3 add into their slice
        float* pr = pool + ks * SLICE;
#pragma unroll
        for (int i = 0; i < 8; ++i)
#pragma unroll
            for (int j = 0; j < 8; ++j)
                pr[(i * 8 + lt) * RROW + j * 8 + le] += acc[i][j];
    }
    __syncthreads();
    // phase2: sum 4 slices, sigmoid+gb, write scores, stash final row in slice 0.
#pragma unroll
    for (int k = 0; k < 2; ++k) {
        const int v  = k * 512 + tid;
        const int t  = v >> 4;
        const int e4 = v & 15;
        float4 s = {0.f, 0.f, 0.f, 0.f};
#pragma unroll
        for (int sl = 0; sl < 4; ++sl) {
            float4 a = *(const float4*)(pool + sl * SLICE + t * RROW + e4 * 4);
            s.x += a.x; s.y += a.y; s.z += a.z; s.w += a.w;
        }
        float4 g = *(const float4*)(gb + e4 * 4);
        float4 r;
        r.x = 1.f / (1.f + expf(-s.x)) + g.x;
        r.y = 1.f / (1.f + expf(-s.y)) + g.y;
        r.z = 1.f / (1.f + expf(-s.z)) + g.z;
        r.w = 1.f / (1.f + expf(-s.w)) + g.w;
        *(float4*)(scores + (size_t)(tok0 + t) * NE + e4 * 4) = r;
        *(float4*)(pool + t * RROW + e4 * 4) = r;
    }
    __syncthreads();

    // ---- fused top-8 + normalize (4 lanes per token; ties -> lower index) ----
    if (tid < 256) {
        const int t  = tid >> 2;       // token 0..63
        const int q4 = tid & 3;
        float v[16];
        const float4* sp = (const float4*)(pool + t * RROW + q4 * 16);
        float4 a = sp[0], b = sp[1], c = sp[2], d = sp[3];
        v[0] = a.x;  v[1] = a.y;  v[2] = a.z;  v[3] = a.w;
        v[4] = b.x;  v[5] = b.y;  v[6] = b.z;  v[7] = b.w;
        v[8] = c.x;  v[9] = c.y;  v[10] = c.z; v[11] = c.w;
        v[12] = d.x; v[13] = d.y; v[14] = d.z; v[15] = d.w;

        float kv[TK]; int ki[TK];
#pragma unroll
        for (int k = 0; k < TK; ++k) {
            float bv = v[0]; int bi = q4 * 16;
#pragma unroll
            for (int j = 1; j < 16; ++j) {
                bool gt = v[j] > bv;
                bv = gt ? v[j] : bv;
                bi = gt ? (q4 * 16 + j) : bi;
            }
#pragma unroll
            for (int off = 1; off < 4; off <<= 1) {
                float ov = __shfl_xor(bv, off);
                int   oi = __shfl_xor(bi, off);
                bool take = (ov > bv) || (ov == bv && oi < bi);
                bv = take ? ov : bv;
                bi = take ? oi : bi;
            }
            int lj = bi - q4 * 16;
#pragma unroll
            for (int j = 0; j < 16; ++j) v[j] = (j == lj) ? -3e38f : v[j];
            kv[k] = bv; ki[k] = bi;
        }

        if (q4 == 0) {
            float s = 0.f;
#pragma unroll
            for (int k = 0; k < TK; ++k) s += kv[k];
            float inv = 1.f / s;
            float* ow = out + (size_t)(tok0 + t) * TK;
            float* oi = out + OUT_I_OFF + (size_t)(tok0 + t) * TK;
#pragma unroll
            for (int k = 0; k < TK; ++k) {
                ow[k] = kv[k] * inv;
                oi[k] = (float)ki[k];
            }
        }
    }
}

extern "C" void kernel_launch(void* const* d_in, const int* in_sizes, int n_in,
                              void* d_out, int out_size, void* d_ws, size_t ws_size,
                              hipStream_t stream) {
    const float* x  = (const float*)d_in[0];
    const float* w  = (const float*)d_in[1];
    const float* gb = (const float*)d_in[2];
    float* out = (float*)d_out;
    (void)in_sizes; (void)n_in; (void)out_size; (void)d_ws; (void)ws_size;

    gate_fused<<<dim3(NTOK / TOKB), dim3(BT), 0, stream>>>(x, w, gb, out);
}